// Round 3
// baseline (177.692 us; speedup 1.0000x reference)
//
#include <hip/hip_runtime.h>
#include <math.h>

#define HW 4096          // 64*64
#define NB 8
#define NC 512
#define NCHUNK 128
#define CPERCHUNK 4      // 512/128

// ---------------------------------------------------------------------------
// Kernel 1: partial 1x1 convs over a 4-channel chunk, contiguous streaming.
// Block = (chunk, b). 256 threads sweep the full 4096-px row in 4 k-subtiles,
// then advance to the next channel -> block reads a CONTIGUOUS 64 KB region
// per tensor (vs 16KB-strided slivers before). 1024 blocks, 32 float4
// loads/thread fully unrolled.
// part layout: part[((chunk*2 + tensor)*NB + b)*HW + p]   (tensor 0=fm,1=x)
// ---------------------------------------------------------------------------
__global__ __launch_bounds__(256, 4) void conv_partial(
    const float* __restrict__ fm, const float* __restrict__ x,
    const float* __restrict__ w1, const float* __restrict__ w2,
    float* __restrict__ part)
{
    const int t     = threadIdx.x;
    const int chunk = blockIdx.x;
    const int b     = blockIdx.y;
    const int c0    = chunk * CPERCHUNK;

    const float* fmb = fm + ((size_t)b * NC + c0) * HW;
    const float* xb  = x  + ((size_t)b * NC + c0) * HW;

    float accf[4][4];   // [k][px]
    float accx[4][4];
    #pragma unroll
    for (int k = 0; k < 4; ++k)
        #pragma unroll
        for (int j = 0; j < 4; ++j) { accf[k][j] = 0.f; accx[k][j] = 0.f; }

    #pragma unroll
    for (int cc = 0; cc < CPERCHUNK; ++cc) {
        const float wa = w1[c0 + cc];
        const float wb = w2[c0 + cc];
        const float* fr = fmb + (size_t)cc * HW + t * 4;
        const float* xr = xb  + (size_t)cc * HW + t * 4;
        #pragma unroll
        for (int k = 0; k < 4; ++k) {
            float4 f = *(const float4*)(fr + k * 1024);
            float4 g = *(const float4*)(xr + k * 1024);
            accf[k][0] = fmaf(f.x, wa, accf[k][0]);
            accf[k][1] = fmaf(f.y, wa, accf[k][1]);
            accf[k][2] = fmaf(f.z, wa, accf[k][2]);
            accf[k][3] = fmaf(f.w, wa, accf[k][3]);
            accx[k][0] = fmaf(g.x, wb, accx[k][0]);
            accx[k][1] = fmaf(g.y, wb, accx[k][1]);
            accx[k][2] = fmaf(g.z, wb, accx[k][2]);
            accx[k][3] = fmaf(g.w, wb, accx[k][3]);
        }
    }

    float* pf = part + ((size_t)(chunk * 2 + 0) * NB + b) * HW + t * 4;
    float* px = part + ((size_t)(chunk * 2 + 1) * NB + b) * HW + t * 4;
    #pragma unroll
    for (int k = 0; k < 4; ++k) {
        *(float4*)(pf + k * 1024) = make_float4(accf[k][0], accf[k][1], accf[k][2], accf[k][3]);
        *(float4*)(px + k * 1024) = make_float4(accx[k][0], accx[k][1], accx[k][2], accx[k][3]);
    }
}

// ---------------------------------------------------------------------------
// Kernel 2: sum the 128 chunk partials, add bias, ReLU. float4 per thread.
// 16384 threads; i -> tensor = i>>13, bhw4 = (i&8191)*4.
// ---------------------------------------------------------------------------
__global__ __launch_bounds__(256) void reduce_bias_relu(
    const float* __restrict__ part,
    const float* __restrict__ b1, const float* __restrict__ b2,
    float* __restrict__ recon, float* __restrict__ refmap)
{
    const int i      = blockIdx.x * 256 + threadIdx.x;   // 0..16383
    const int tensor = i >> 13;                           // 0 or 1
    const int bhw4   = (i & 8191) * 4;

    float s0 = 0.f, s1 = 0.f, s2 = 0.f, s3 = 0.f;
    #pragma unroll 8
    for (int ch = 0; ch < NCHUNK; ++ch) {
        float4 v = *(const float4*)(part + (size_t)(ch * 2 + tensor) * (NB * HW) + bhw4);
        s0 += v.x; s1 += v.y; s2 += v.z; s3 += v.w;
    }

    const float bias = (tensor == 0) ? b1[0] : b2[0];
    float4 r = make_float4(fmaxf(s0 + bias, 0.f), fmaxf(s1 + bias, 0.f),
                           fmaxf(s2 + bias, 0.f), fmaxf(s3 + bias, 0.f));
    if (tensor == 0) *(float4*)(recon + bhw4)  = r;
    else             *(float4*)(refmap + bhw4) = r;
}

// ---------------------------------------------------------------------------
// Kernel 3: correlation argmax + gather + fold.
// One wave per patch; 4 waves (4 patches) per block; 2048 blocks = 8 b * 256.
// gg in LDS: 65x65 zero-padded recon, stride 65 (bank = (p+q)%32, conflict-free).
// ---------------------------------------------------------------------------
__global__ __launch_bounds__(256) void correlate_gather(
    const float* __restrict__ recon, const float* __restrict__ refmap,
    float* __restrict__ out)
{
    __shared__ float gg[65 * 65];

    const int b     = blockIdx.x >> 8;          // 256 blocks per batch
    const int pbase = (blockIdx.x & 255) * 4;   // 4 patches per block
    const int t     = threadIdx.x;

    // stage zero-padded recon for this batch into LDS
    const float* rb = recon + (size_t)b * HW;
    for (int i = t; i < 65 * 65; i += 256) {
        const int r = i / 65;
        const int c = i - r * 65;
        gg[i] = (r < 64 && c < 64) ? rb[r * 64 + c] : 0.f;
    }
    __syncthreads();

    const int wave = t >> 6;
    const int lane = t & 63;
    const int l    = pbase + wave;       // patch index in [0,1024)
    const int ph   = l >> 5;
    const int pw   = l & 31;

    // 2x2 kernel from refmap patch l (wave-uniform addresses)
    const float* km = refmap + (size_t)b * HW + (ph * 2) * 64 + pw * 2;
    const float k00 = km[0], k01 = km[1], k10 = km[64], k11 = km[65];

    // lane handles window row p = lane; slide over q, reusing right->left
    const int p = lane;
    const float* row0 = gg + p * 65;
    const float* row1 = row0 + 65;

    float best = -INFINITY;
    int   bpos = 0;
    float a  = row0[0];
    float cv = row1[0];
    #pragma unroll
    for (int q = 0; q < 64; ++q) {
        const float bv = row0[q + 1];
        const float dv = row1[q + 1];
        // term order matches einsum reduction order (c, di, dj)
        float v = k00 * a;
        v = fmaf(k01, bv, v);
        v = fmaf(k10, cv, v);
        v = fmaf(k11, dv, v);
        const int pos = p * 64 + q;
        if (v > best) { best = v; bpos = pos; }   // strict > = first-max-wins within lane
        a  = bv;
        cv = dv;
    }

    // butterfly reduce across 64 lanes: max value, min position on ties
    #pragma unroll
    for (int m = 1; m < 64; m <<= 1) {
        const float ov = __shfl_xor(best, m, 64);
        const int   op = __shfl_xor(bpos, m, 64);
        if (ov > best || (ov == best && op < bpos)) { best = ov; bpos = op; }
    }

    if (lane == 0) {
        const int idx = bpos >> 2;       // offset // 4
        const int ph2 = idx >> 5;
        const int pw2 = idx & 31;
        const float* src = gg + (ph2 * 2) * 65 + pw2 * 2;   // recon patch idx
        float* o = out + (size_t)b * HW + (ph * 2) * 64 + pw * 2;
        o[0]  = src[0];
        o[1]  = src[1];
        o[64] = src[65];
        o[65] = src[66];
    }
}

// ---------------------------------------------------------------------------
extern "C" void kernel_launch(void* const* d_in, const int* in_sizes, int n_in,
                              void* d_out, int out_size, void* d_ws, size_t ws_size,
                              hipStream_t stream)
{
    const float* spade_fm = (const float*)d_in[0];
    const float* x        = (const float*)d_in[1];
    const float* w1       = (const float*)d_in[2];
    const float* b1       = (const float*)d_in[3];
    const float* w2       = (const float*)d_in[4];
    const float* b2       = (const float*)d_in[5];
    float* out = (float*)d_out;

    float* part   = (float*)d_ws;                 // 128*2*8*4096 floats = 33.5 MB
    float* recon  = part + (size_t)NCHUNK * 2 * NB * HW;
    float* refmap = recon + NB * HW;

    dim3 g1(NCHUNK, NB);
    conv_partial<<<g1, 256, 0, stream>>>(spade_fm, x, w1, w2, part);
    reduce_bias_relu<<<64, 256, 0, stream>>>(part, b1, b2, recon, refmap);
    correlate_gather<<<2048, 256, 0, stream>>>(recon, refmap, out);
}

// Round 4
// 169.490 us; speedup vs baseline: 1.0484x; 1.0484x over previous
//
#include <hip/hip_runtime.h>
#include <math.h>

#define HW 4096          // 64*64
#define NB 8
#define NC 512
#define NCHUNK 32
#define CPERCHUNK 16     // 512/32

// ---------------------------------------------------------------------------
// Kernel 1: partial 1x1 convs over a 16-channel chunk.
// grid (hw_tile=4, chunk=32, b=8) = 1024 blocks.
// KEY: all 32 float4 loads are issued into explicit register arrays BEFORE
// any FMA consumes them -> compiler emits one descending vmcnt chain
// (32 loads in flight per wave) instead of vmcnt(0)-per-load serialization
// (R2/R3 showed VGPR_Count=32 => ~1 load in flight => 2 TB/s wall).
// part layout: part[(chunk*2 + tensor)*32768 + b*4096 + hw]   (tensor 0=fm,1=x)
// ---------------------------------------------------------------------------
__global__ __launch_bounds__(256, 3) void conv_partial(
    const float* __restrict__ fm, const float* __restrict__ x,
    const float* __restrict__ w1, const float* __restrict__ w2,
    float* __restrict__ part)
{
    const int t     = threadIdx.x;
    const int hw4   = blockIdx.x * 1024 + t * 4;   // 4 consecutive pixels
    const int chunk = blockIdx.y;
    const int b     = blockIdx.z;
    const int c0    = chunk * CPERCHUNK;

    const float* fmb = fm + ((size_t)b * NC + c0) * HW + hw4;
    const float* xb  = x  + ((size_t)b * NC + c0) * HW + hw4;

    // ---- load phase: 32 independent dwordx4 loads, all in flight ----
    float4 fbuf[CPERCHUNK];
    float4 gbuf[CPERCHUNK];
    #pragma unroll
    for (int cc = 0; cc < CPERCHUNK; ++cc)
        fbuf[cc] = *(const float4*)(fmb + (size_t)cc * HW);
    #pragma unroll
    for (int cc = 0; cc < CPERCHUNK; ++cc)
        gbuf[cc] = *(const float4*)(xb + (size_t)cc * HW);

    // ---- consume phase: in load order, so waitcnt drains progressively ----
    float af0 = 0.f, af1 = 0.f, af2 = 0.f, af3 = 0.f;
    float ax0 = 0.f, ax1 = 0.f, ax2 = 0.f, ax3 = 0.f;
    #pragma unroll
    for (int cc = 0; cc < CPERCHUNK; ++cc) {
        const float wa = w1[c0 + cc];
        af0 = fmaf(fbuf[cc].x, wa, af0);
        af1 = fmaf(fbuf[cc].y, wa, af1);
        af2 = fmaf(fbuf[cc].z, wa, af2);
        af3 = fmaf(fbuf[cc].w, wa, af3);
    }
    #pragma unroll
    for (int cc = 0; cc < CPERCHUNK; ++cc) {
        const float wb = w2[c0 + cc];
        ax0 = fmaf(gbuf[cc].x, wb, ax0);
        ax1 = fmaf(gbuf[cc].y, wb, ax1);
        ax2 = fmaf(gbuf[cc].z, wb, ax2);
        ax3 = fmaf(gbuf[cc].w, wb, ax3);
    }

    float* pf = part + ((size_t)(chunk * 2 + 0) * NB + b) * HW + hw4;
    float* px = part + ((size_t)(chunk * 2 + 1) * NB + b) * HW + hw4;
    *(float4*)pf = make_float4(af0, af1, af2, af3);
    *(float4*)px = make_float4(ax0, ax1, ax2, ax3);
}

// ---------------------------------------------------------------------------
// Kernel 2: sum the 32 chunk partials, add bias, ReLU. float4 per thread,
// 32-load register batch (same anti-serialization treatment).
// 16384 threads; i -> tensor = i>>13, bhw4 = (i&8191)*4.
// Summation order ch=0..31 matches R2 (absmax was exactly 0.0).
// ---------------------------------------------------------------------------
__global__ __launch_bounds__(256, 3) void reduce_bias_relu(
    const float* __restrict__ part,
    const float* __restrict__ b1, const float* __restrict__ b2,
    float* __restrict__ recon, float* __restrict__ refmap)
{
    const int i      = blockIdx.x * 256 + threadIdx.x;   // 0..16383
    const int tensor = i >> 13;                           // 0 or 1
    const int bhw4   = (i & 8191) * 4;

    float4 buf[NCHUNK];
    #pragma unroll
    for (int ch = 0; ch < NCHUNK; ++ch)
        buf[ch] = *(const float4*)(part + (size_t)(ch * 2 + tensor) * (NB * HW) + bhw4);

    float s0 = 0.f, s1 = 0.f, s2 = 0.f, s3 = 0.f;
    #pragma unroll
    for (int ch = 0; ch < NCHUNK; ++ch) {
        s0 += buf[ch].x; s1 += buf[ch].y; s2 += buf[ch].z; s3 += buf[ch].w;
    }

    const float bias = (tensor == 0) ? b1[0] : b2[0];
    float4 r = make_float4(fmaxf(s0 + bias, 0.f), fmaxf(s1 + bias, 0.f),
                           fmaxf(s2 + bias, 0.f), fmaxf(s3 + bias, 0.f));
    if (tensor == 0) *(float4*)(recon + bhw4)  = r;
    else             *(float4*)(refmap + bhw4) = r;
}

// ---------------------------------------------------------------------------
// Kernel 3: correlation argmax + gather + fold.
// One wave per patch; 4 waves (4 patches) per block; 2048 blocks = 8 b * 256.
// gg in LDS: 65x65 zero-padded recon, stride 65 (bank = (p+q)%32, conflict-free).
// ---------------------------------------------------------------------------
__global__ __launch_bounds__(256) void correlate_gather(
    const float* __restrict__ recon, const float* __restrict__ refmap,
    float* __restrict__ out)
{
    __shared__ float gg[65 * 65];

    const int b     = blockIdx.x >> 8;          // 256 blocks per batch
    const int pbase = (blockIdx.x & 255) * 4;   // 4 patches per block
    const int t     = threadIdx.x;

    // stage zero-padded recon for this batch into LDS
    const float* rb = recon + (size_t)b * HW;
    for (int i = t; i < 65 * 65; i += 256) {
        const int r = i / 65;
        const int c = i - r * 65;
        gg[i] = (r < 64 && c < 64) ? rb[r * 64 + c] : 0.f;
    }
    __syncthreads();

    const int wave = t >> 6;
    const int lane = t & 63;
    const int l    = pbase + wave;       // patch index in [0,1024)
    const int ph   = l >> 5;
    const int pw   = l & 31;

    // 2x2 kernel from refmap patch l (wave-uniform addresses)
    const float* km = refmap + (size_t)b * HW + (ph * 2) * 64 + pw * 2;
    const float k00 = km[0], k01 = km[1], k10 = km[64], k11 = km[65];

    // lane handles window row p = lane; slide over q, reusing right->left
    const int p = lane;
    const float* row0 = gg + p * 65;
    const float* row1 = row0 + 65;

    float best = -INFINITY;
    int   bpos = 0;
    float a  = row0[0];
    float cv = row1[0];
    #pragma unroll
    for (int q = 0; q < 64; ++q) {
        const float bv = row0[q + 1];
        const float dv = row1[q + 1];
        // term order matches einsum reduction order (c, di, dj)
        float v = k00 * a;
        v = fmaf(k01, bv, v);
        v = fmaf(k10, cv, v);
        v = fmaf(k11, dv, v);
        const int pos = p * 64 + q;
        if (v > best) { best = v; bpos = pos; }   // strict > = first-max-wins within lane
        a  = bv;
        cv = dv;
    }

    // butterfly reduce across 64 lanes: max value, min position on ties
    #pragma unroll
    for (int m = 1; m < 64; m <<= 1) {
        const float ov = __shfl_xor(best, m, 64);
        const int   op = __shfl_xor(bpos, m, 64);
        if (ov > best || (ov == best && op < bpos)) { best = ov; bpos = op; }
    }

    if (lane == 0) {
        const int idx = bpos >> 2;       // offset // 4
        const int ph2 = idx >> 5;
        const int pw2 = idx & 31;
        const float* src = gg + (ph2 * 2) * 65 + pw2 * 2;   // recon patch idx
        float* o = out + (size_t)b * HW + (ph * 2) * 64 + pw * 2;
        o[0]  = src[0];
        o[1]  = src[1];
        o[64] = src[65];
        o[65] = src[66];
    }
}

// ---------------------------------------------------------------------------
extern "C" void kernel_launch(void* const* d_in, const int* in_sizes, int n_in,
                              void* d_out, int out_size, void* d_ws, size_t ws_size,
                              hipStream_t stream)
{
    const float* spade_fm = (const float*)d_in[0];
    const float* x        = (const float*)d_in[1];
    const float* w1       = (const float*)d_in[2];
    const float* b1       = (const float*)d_in[3];
    const float* w2       = (const float*)d_in[4];
    const float* b2       = (const float*)d_in[5];
    float* out = (float*)d_out;

    float* part   = (float*)d_ws;                 // 64 * 32768 floats = 8 MB
    float* recon  = part + NCHUNK * 2 * 32768;    // 8*4096 floats
    float* refmap = recon + NB * HW;              // 8*4096 floats

    dim3 g1(4, NCHUNK, NB);
    conv_partial<<<g1, 256, 0, stream>>>(spade_fm, x, w1, w2, part);
    reduce_bias_relu<<<64, 256, 0, stream>>>(part, b1, b2, recon, refmap);
    correlate_gather<<<2048, 256, 0, stream>>>(recon, refmap, out);
}

// Round 5
// 168.261 us; speedup vs baseline: 1.0561x; 1.0073x over previous
//
#include <hip/hip_runtime.h>
#include <math.h>
#include <stdint.h>

#define HW 4096          // 64*64
#define NB 8
#define NC 512
#define NCHUNK 32
#define CPERCHUNK 16     // 512/32
#define TP 256           // pixels per staging block

// async global->LDS: each lane supplies its own 16B-aligned global address;
// LDS destination is WAVE-UNIFORM base, HW writes lane i at base + i*16.
#define ASYNC_1KB(gsrc, ldsbase)                                             \
    __builtin_amdgcn_global_load_lds(                                        \
        (const __attribute__((address_space(1))) uint32_t*)(gsrc),           \
        (__attribute__((address_space(3))) uint32_t*)(ldsbase), 16, 0, 0)

// ---------------------------------------------------------------------------
// Kernel 1: partial 1x1 convs. grid (pxtile=16, chunk=32, b=8) = 4096 blocks.
// Each block async-stages 16 ch x 256 px x 2 tensors = 32 KB via
// global_load_lds (8 x 1KB fire-and-forget copies per wave -> loads stay in
// flight by construction; R2-R4 showed VGPR-destined loads get vmcnt(0)
// serialized at ~3 TB/s). Then one barrier, 32 FMAs/thread, 2 stores.
// part layout: part[(chunk*2 + tensor)*32768 + b*4096 + hw]   (tensor 0=fm,1=x)
// ---------------------------------------------------------------------------
__global__ __launch_bounds__(256) void conv_partial(
    const float* __restrict__ fm, const float* __restrict__ x,
    const float* __restrict__ w1, const float* __restrict__ w2,
    float* __restrict__ part)
{
    __shared__ float lds[2 * CPERCHUNK * TP];   // 32 KB: [tensor][ch][px]

    const int t     = threadIdx.x;
    const int lane  = t & 63;
    const int wv    = t >> 6;
    const int hw0   = blockIdx.x * TP;
    const int chunk = blockIdx.y;
    const int b     = blockIdx.z;
    const int c0    = chunk * CPERCHUNK;

    // 8 async 1KB channel-segments per wave; L = wv*8+i in [0,32)
    #pragma unroll
    for (int i = 0; i < 8; ++i) {
        const int L      = wv * 8 + i;
        const int tensor = L >> 4;          // wave-uniform
        const int ch     = L & 15;
        const float* g = (tensor ? x : fm)
                       + ((size_t)(b * NC + c0 + ch)) * HW + hw0 + lane * 4;
        float* l = lds + tensor * (CPERCHUNK * TP) + ch * TP;
        ASYNC_1KB(g, l);
    }
    __syncthreads();   // drains vmcnt(0) before barrier

    // accumulate channels ascending (same order as R2/R4 -> identical numerics)
    float af = 0.f, ax = 0.f;
    #pragma unroll
    for (int c = 0; c < CPERCHUNK; ++c) {
        af = fmaf(lds[c * TP + t],                     w1[c0 + c], af);
        ax = fmaf(lds[CPERCHUNK * TP + c * TP + t],    w2[c0 + c], ax);
    }
    part[((size_t)(chunk * 2 + 0) * NB + b) * HW + hw0 + t] = af;
    part[((size_t)(chunk * 2 + 1) * NB + b) * HW + hw0 + t] = ax;
}

// ---------------------------------------------------------------------------
// Kernel 2: sum 32 chunk partials + bias + ReLU, same async-staging machinery.
// grid (pxtile=16, tensor*8+b=16) = 256 blocks, 32 KB LDS each.
// Chunk sum ascending = bit-identical grouping to R4 (proven absmax 0.0).
// ---------------------------------------------------------------------------
__global__ __launch_bounds__(256) void reduce_bias_relu(
    const float* __restrict__ part,
    const float* __restrict__ b1, const float* __restrict__ b2,
    float* __restrict__ recon, float* __restrict__ refmap)
{
    __shared__ float lds[NCHUNK * TP];   // 32 KB

    const int t      = threadIdx.x;
    const int lane   = t & 63;
    const int wv     = t >> 6;
    const int px0    = blockIdx.x * TP;
    const int tensor = blockIdx.y >> 3;
    const int b      = blockIdx.y & 7;

    #pragma unroll
    for (int i = 0; i < 8; ++i) {
        const int ch = wv * 8 + i;
        const float* g = part + ((size_t)(ch * 2 + tensor) * NB + b) * HW
                       + px0 + lane * 4;
        ASYNC_1KB(g, lds + ch * TP);
    }
    __syncthreads();

    float s = 0.f;
    #pragma unroll
    for (int ch = 0; ch < NCHUNK; ++ch)
        s += lds[ch * TP + t];

    const float r = fmaxf(s + (tensor ? b2[0] : b1[0]), 0.f);
    float* dst = tensor ? refmap : recon;
    dst[(size_t)b * HW + px0 + t] = r;
}

// ---------------------------------------------------------------------------
// Kernel 3: correlation argmax + gather + fold.
// 256 blocks (8 b x 32), 32 patches/block = 8 patches/wave, q-loop hoisted:
// window rows are read from LDS ONCE per q and reused across 8 patches
// (LDS traffic /8 vs R4), staging redundancy 8 -> 1 per 32 patches.
// Scan order & tie-break identical to R4 (proven exact).
// ---------------------------------------------------------------------------
__global__ __launch_bounds__(256) void correlate_gather(
    const float* __restrict__ recon, const float* __restrict__ refmap,
    float* __restrict__ out)
{
    __shared__ float gg[65 * 65];

    const int t  = threadIdx.x;
    const int b  = blockIdx.x >> 5;
    const int pb = (blockIdx.x & 31) * 32;

    // stage zero-padded recon (float4 global reads, scalar LDS writes)
    const float* rb = recon + (size_t)b * HW;
    #pragma unroll
    for (int i = 0; i < 4; ++i) {
        const int idx = (t + i * 256) * 4;     // 0..4092, float4-aligned
        const int r = idx >> 6;
        const int c = idx & 63;
        float4 v = *(const float4*)(rb + idx);
        float* d = gg + r * 65 + c;
        d[0] = v.x; d[1] = v.y; d[2] = v.z; d[3] = v.w;
    }
    if (t < 65) gg[64 * 65 + t] = 0.f;
    if (t < 64) gg[t * 65 + 64] = 0.f;
    __syncthreads();

    const int wv   = t >> 6;
    const int lane = t & 63;
    const int p    = lane;                      // window row handled by lane
    const float* row0 = gg + p * 65;
    const float* row1 = row0 + 65;

    // preload this wave's 8 patch kernels (2x2 each)
    float k00[8], k01[8], k10[8], k11[8];
    #pragma unroll
    for (int i = 0; i < 8; ++i) {
        const int l  = pb + wv * 8 + i;
        const int ph = l >> 5, pw = l & 31;
        const float* km = refmap + (size_t)b * HW + (ph * 2) * 64 + pw * 2;
        k00[i] = km[0]; k01[i] = km[1]; k10[i] = km[64]; k11[i] = km[65];
    }

    float best[8]; int bq[8];
    #pragma unroll
    for (int i = 0; i < 8; ++i) { best[i] = -INFINITY; bq[i] = 0; }

    float a  = row0[0];
    float cv = row1[0];
    #pragma unroll 4
    for (int q = 0; q < 64; ++q) {
        const float bvv = row0[q + 1];
        const float dv  = row1[q + 1];
        #pragma unroll
        for (int i = 0; i < 8; ++i) {
            // term order matches einsum reduction order (c, di, dj)
            float v = k00[i] * a;
            v = fmaf(k01[i], bvv, v);
            v = fmaf(k10[i], cv,  v);
            v = fmaf(k11[i], dv,  v);
            if (v > best[i]) { best[i] = v; bq[i] = q; }  // first-max within lane
        }
        a = bvv; cv = dv;
    }

    #pragma unroll
    for (int i = 0; i < 8; ++i) {
        float bv  = best[i];
        int  bpos = p * 64 + bq[i];
        #pragma unroll
        for (int m = 1; m < 64; m <<= 1) {
            const float ov = __shfl_xor(bv, m, 64);
            const int   op = __shfl_xor(bpos, m, 64);
            if (ov > bv || (ov == bv && op < bpos)) { bv = ov; bpos = op; }
        }
        if (lane == 0) {
            const int idx = bpos >> 2;          // offset // 4
            const int ph2 = idx >> 5, pw2 = idx & 31;
            const float* src = gg + (ph2 * 2) * 65 + pw2 * 2;
            const int l  = pb + wv * 8 + i;
            const int ph = l >> 5, pw = l & 31;
            float* o = out + (size_t)b * HW + (ph * 2) * 64 + pw * 2;
            o[0]  = src[0];
            o[1]  = src[1];
            o[64] = src[65];
            o[65] = src[66];
        }
    }
}

// ---------------------------------------------------------------------------
extern "C" void kernel_launch(void* const* d_in, const int* in_sizes, int n_in,
                              void* d_out, int out_size, void* d_ws, size_t ws_size,
                              hipStream_t stream)
{
    const float* spade_fm = (const float*)d_in[0];
    const float* x        = (const float*)d_in[1];
    const float* w1       = (const float*)d_in[2];
    const float* b1       = (const float*)d_in[3];
    const float* w2       = (const float*)d_in[4];
    const float* b2       = (const float*)d_in[5];
    float* out = (float*)d_out;

    float* part   = (float*)d_ws;                 // 64 * 32768 floats = 8 MB
    float* recon  = part + NCHUNK * 2 * 32768;    // 8*4096 floats
    float* refmap = recon + NB * HW;              // 8*4096 floats

    dim3 g1(HW / TP, NCHUNK, NB);                 // (16, 32, 8) = 4096 blocks
    conv_partial<<<g1, 256, 0, stream>>>(spade_fm, x, w1, w2, part);
    reduce_bias_relu<<<dim3(HW / TP, 16), 256, 0, stream>>>(part, b1, b2, recon, refmap);
    correlate_gather<<<256, 256, 0, stream>>>(recon, refmap, out);
}